// Round 16
// baseline (516.199 us; speedup 1.0000x reference)
//
#include <hip/hip_runtime.h>

using u16 = unsigned short;
typedef float f32x4 __attribute__((ext_vector_type(4)));
typedef float f32x16 __attribute__((ext_vector_type(16)));
typedef __bf16 bf16x8 __attribute__((ext_vector_type(8)));
typedef u16 u16x8 __attribute__((ext_vector_type(8)));
typedef u16 u16x4 __attribute__((ext_vector_type(4)));

// dims: B=64, S=2048, ENC=1024, U=512, E=256, V=50000, IN=1280
// scratch layout (float units)
static constexpr int OF_HPB   = 262144;    // w1p: 512K u16
static constexpr int OF_CTXP  = 294912;    // hpb: 64*512
static constexpr int OF_STATS = 2392064;   // ctxp: 2048*1024 f32
static constexpr int OF_XIN   = 2394112;   // stats: 2048
static constexpr int OF_ZPART = 2476032;   // xin: 64*1280
static constexpr int OF_HHL   = 3000320;   // zpart: 4*64*2048; hhl: 2*64*1024 u16
static constexpr size_t SCRATCH_FLOATS = 3065856;
static constexpr size_t SCRATCH_BYTES  = SCRATCH_FLOATS * 4ull;   // ~12.3 MB

__device__ __forceinline__ u16 f2bf(float f) {
  unsigned u = __float_as_uint(f);
  u += 0x7FFFu + ((u >> 16) & 1u);   // RNE; inputs finite
  return (u16)(u >> 16);
}
__device__ __forceinline__ float bf2f(u16 u) {
  return __uint_as_float((unsigned)u << 16);
}
__device__ __forceinline__ float fast_tanh(float x) {
  x = fminf(fmaxf(x, -20.f), 20.f);
  float e = __expf(2.f * x);
  return (e - 1.f) / (e + 1.f);
}
__device__ __forceinline__ float fast_sig(float x) { return 1.f / (1.f + __expf(-x)); }

// ---------------- merged prep: blocks 0..63 pack W1 -> w1p; blocks 64..127 compute hpb
// w1p[ks16*8192 + (ug*64 + l)*8 + e] = W1[ks16*16 + (l>>5)*8 + e][ug*32 + (l&31)]
__global__ void k_prep(const float* __restrict__ W1w, u16* __restrict__ w1p,
                       const float* __restrict__ cf, const float* __restrict__ cb,
                       const float* __restrict__ W2w, const float* __restrict__ W2b,
                       const float* __restrict__ W3w, const float* __restrict__ W3b,
                       const float* __restrict__ W1b, float* __restrict__ hpb) {
  __shared__ float tile[16][516];
  const int t = threadIdx.x;
  if (blockIdx.x < 64) {
    const int ks = blockIdx.x;
    {
      int kk = t >> 4, u0 = (t & 15) * 32;
      const float* src = W1w + (size_t)(ks * 16 + kk) * 512 + u0;
      #pragma unroll
      for (int i = 0; i < 8; ++i)
        *(float4*)&tile[kk][u0 + i * 4] = *(const float4*)(src + i * 4);
    }
    __syncthreads();
    #pragma unroll
    for (int q = 0; q < 4; ++q) {
      int c = t + q * 256;              // chunk 0..1023
      int ug = c >> 6, l = c & 63;
      int u = ug * 32 + (l & 31), koct = l >> 5;
      u16x8 p;
      #pragma unroll
      for (int e = 0; e < 8; ++e) p[e] = f2bf(tile[koct * 8 + e][u]);
      *(u16x8*)(w1p + (size_t)ks * 8192 + (size_t)c * 8) = p;
    }
  } else {
    float* cfl = &tile[0][0];
    float* cbl = &tile[0][0] + 512;
    const int b = blockIdx.x - 64;
    cfl[t] = cf[(size_t)b * 512 + t];       cfl[t + 256] = cf[(size_t)b * 512 + t + 256];
    cbl[t] = cb[(size_t)b * 512 + t];       cbl[t + 256] = cb[(size_t)b * 512 + t + 256];
    __syncthreads();
    const int u1 = t, u2 = t + 256;
    float a1 = W2b[u1] + W3b[u1] + W1b[u1];
    float a2 = W2b[u2] + W3b[u2] + W1b[u2];
    for (int k = 0; k < 512; ++k) {
      float c1 = cfl[k], c2 = cbl[k];
      const float* r2 = W2w + (size_t)k * 512;
      const float* r3 = W3w + (size_t)k * 512;
      a1 += c1 * r2[u1] + c2 * r3[u1];
      a2 += c1 * r2[u2] + c2 * r3[u2];
    }
    hpb[(size_t)b * 512 + u1] = a1;
    hpb[(size_t)b * 512 + u2] = a2;
  }
}

// ---------------- fused attention v9b: r15 (tied-best) + T5 setprio around MFMA.
// 2048 blocks = 64 b x 32 tiles (64 rows). 512 thr = 8 waves, wave tile 64x64
// (acc[2][2], 64 acc regs, 4 blocks/CU target). Macro-BK=64: 16 macros, one
// lgkm-only s_barrier each. A prefetch 1-deep regs; B direct per k-step (L2-hot).
__global__ void __launch_bounds__(512, 4)
k_attn(const float* __restrict__ enc, const u16* __restrict__ w1p,
       const float* __restrict__ hpb, const float* __restrict__ Vw,
       const float* __restrict__ Vb, float* __restrict__ ctxp,
       float* __restrict__ stats) {
  __shared__ __align__(16) u16 smem[8448];   // A dbuf 2x4128 u16; epi 3712 f32

  const int t = threadIdx.x;
  const int bid = blockIdx.x;
  const int b = bid >> 5, tile = bid & 31;
  const size_t row0 = (size_t)b * 2048 + (size_t)tile * 64;

  const int l = t & 63, wv = t >> 6;   // 8 waves; wave wv: rows 0..63 x u [wv*64,+64)

  const u16* bbase = w1p + (size_t)(wv * 2) * 512 + (size_t)l * 8;  // + ks*8192; b1=+512

  // staging: t -> row sr(64), k-octet sq8(8); 2 float4 loads -> 1 u16x8 LDS write
  const int sr = t >> 3, sq8 = t & 7;
  const int sksl = sq8 >> 1, skoct = sq8 & 1;
  const float* a_src = enc + (row0 + sr) * 1024 + sq8 * 8;    // + km*64
  const int a_dst = sksl * 1032 + (sr >> 5) * 512 + ((sr & 31) + skoct * 32) * 8;

  f32x16 acc00, acc01, acc10, acc11;
  #pragma unroll
  for (int i = 0; i < 16; ++i) { acc00[i]=0.f; acc01[i]=0.f; acc10[i]=0.f; acc11[i]=0.f; }

  float4 p00, p01;
  {  // prologue: stage macro0 directly; macro1 loads in flight
    float4 v0 = *(const float4*)(a_src);
    float4 v1 = *(const float4*)(a_src + 4);
    u16x8 pk;
    pk[0]=f2bf(v0.x); pk[1]=f2bf(v0.y); pk[2]=f2bf(v0.z); pk[3]=f2bf(v0.w);
    pk[4]=f2bf(v1.x); pk[5]=f2bf(v1.y); pk[6]=f2bf(v1.z); pk[7]=f2bf(v1.w);
    *(u16x8*)(smem + a_dst) = pk;
    p00 = *(const float4*)(a_src + 64);
    p01 = *(const float4*)(a_src + 68);
  }
  asm volatile("s_waitcnt lgkmcnt(0)" ::: "memory");
  __builtin_amdgcn_s_barrier();
  __builtin_amdgcn_sched_barrier(0);

  for (int km = 0; km < 16; ++km) {
    const int cur = km & 1;
    if (km < 15) {                 // stage A(km+1) (loaded last iter)
      u16x8 pk;
      pk[0]=f2bf(p00.x); pk[1]=f2bf(p00.y); pk[2]=f2bf(p00.z); pk[3]=f2bf(p00.w);
      pk[4]=f2bf(p01.x); pk[5]=f2bf(p01.y); pk[6]=f2bf(p01.z); pk[7]=f2bf(p01.w);
      *(u16x8*)(smem + (cur ^ 1) * 4128 + a_dst) = pk;
      if (km < 14) {               // issue A(km+2)
        const float* sp = a_src + (km + 2) * 64;
        p00 = *(const float4*)(sp);
        p01 = *(const float4*)(sp + 4);
      }
    }
    const u16* Ac = smem + cur * 4128;
    __builtin_amdgcn_s_setprio(1);   // T5: favor MFMA-issuing waves vs staging waves
    #pragma unroll
    for (int m = 0; m < 4; ++m) {
      bf16x8 a0 = *(const bf16x8*)(Ac + m * 1032 + l * 8);          // rows 0..31
      bf16x8 a1 = *(const bf16x8*)(Ac + m * 1032 + 512 + l * 8);    // rows 32..63
      const u16* bp = bbase + (size_t)(km * 4 + m) * 8192;
      bf16x8 b0 = *(const bf16x8*)(bp);           // u [wv*64, +32)
      bf16x8 b1 = *(const bf16x8*)(bp + 512);     // u [wv*64+32, +32)
      acc00 = __builtin_amdgcn_mfma_f32_32x32x16_bf16(a0, b0, acc00, 0, 0, 0);
      acc01 = __builtin_amdgcn_mfma_f32_32x32x16_bf16(a0, b1, acc01, 0, 0, 0);
      acc10 = __builtin_amdgcn_mfma_f32_32x32x16_bf16(a1, b0, acc10, 0, 0, 0);
      acc11 = __builtin_amdgcn_mfma_f32_32x32x16_bf16(a1, b1, acc11, 0, 0, 0);
    }
    __builtin_amdgcn_s_setprio(0);
    asm volatile("s_waitcnt lgkmcnt(0)" ::: "memory");
    __builtin_amdgcn_s_barrier();
    __builtin_amdgcn_sched_barrier(0);
  }

  // ---- epilogue (smem reused as f32): score -> exp -> stats
  float* fsm = (float*)smem;
  float* red = fsm;            // [64][9]
  float* scv = fsm + 576;      // [64]
  float* pcv = fsm + 640;      // [3][1024]

  {
    const int lu = l & 31;
    const float vw0 = Vw[wv * 64 + lu];
    const float vw1 = Vw[wv * 64 + 32 + lu];
    const float hp0 = hpb[(size_t)b * 512 + wv * 64 + lu];
    const float hp1 = hpb[(size_t)b * 512 + wv * 64 + 32 + lu];
    const int hi4 = (l >> 5) * 4;
    const bool writer = (lu == 0);
    // D mapping (32x32): col=lane&31 (u), row=(r&3)+8*(r>>2)+4*(lane>>5) (s)
    #pragma unroll
    for (int mi = 0; mi < 2; ++mi) {
      #pragma unroll
      for (int r = 0; r < 16; ++r) {
        float s = vw0 * fast_tanh((mi ? acc10[r] : acc00[r]) + hp0)
                + vw1 * fast_tanh((mi ? acc11[r] : acc01[r]) + hp1);
        s += __shfl_xor(s, 1);
        s += __shfl_xor(s, 2);
        s += __shfl_xor(s, 4);
        s += __shfl_xor(s, 8);
        s += __shfl_xor(s, 16);
        if (writer) {
          int row = mi * 32 + (r & 3) + 8 * (r >> 2) + hi4;
          red[row * 9 + wv] = s;
        }
      }
    }
  }
  __syncthreads();
  if (t < 64) {
    float s = Vb[0];
    #pragma unroll
    for (int wq = 0; wq < 8; ++wq) s += red[t * 9 + wq];
    float e = __expf(s);   // |score| bounded (~||Vw||_1): f32-safe without max-sub
    scv[t] = e;
    float p = e;
    p += __shfl_xor(p, 1);  p += __shfl_xor(p, 2);  p += __shfl_xor(p, 4);
    p += __shfl_xor(p, 8);  p += __shfl_xor(p, 16); p += __shfl_xor(p, 32);
    if (t == 0) stats[bid] = p;
  }
  __syncthreads();

  // ---- tail-PV: unnormalized partial ctx from own (L3-hot) f32 enc tile
  {
    const int c8 = (t & 127) * 8;
    const int rq = t >> 7;               // 0..3 -> rows rq*16..+16
    const float* ep = enc + (row0 + rq * 16) * 1024 + c8;
    float a8[8] = {0.f,0.f,0.f,0.f,0.f,0.f,0.f,0.f};
    #pragma unroll 4
    for (int r = 0; r < 16; ++r) {
      float4 v0 = *(const float4*)(ep + (size_t)r * 1024);
      float4 v1 = *(const float4*)(ep + (size_t)r * 1024 + 4);
      float sc = scv[rq * 16 + r];
      a8[0] += sc * v0.x; a8[1] += sc * v0.y; a8[2] += sc * v0.z; a8[3] += sc * v0.w;
      a8[4] += sc * v1.x; a8[5] += sc * v1.y; a8[6] += sc * v1.z; a8[7] += sc * v1.w;
    }
    if (rq) {
      float4 s0 = {a8[0], a8[1], a8[2], a8[3]};
      float4 s1 = {a8[4], a8[5], a8[6], a8[7]};
      *(float4*)&pcv[(rq - 1) * 1024 + c8] = s0;
      *(float4*)&pcv[(rq - 1) * 1024 + c8 + 4] = s1;
    }
    __syncthreads();
    if (rq == 0) {
      float4 o0, o1;
      o0.x = a8[0] + pcv[c8+0] + pcv[1024+c8+0] + pcv[2048+c8+0];
      o0.y = a8[1] + pcv[c8+1] + pcv[1024+c8+1] + pcv[2048+c8+1];
      o0.z = a8[2] + pcv[c8+2] + pcv[1024+c8+2] + pcv[2048+c8+2];
      o0.w = a8[3] + pcv[c8+3] + pcv[1024+c8+3] + pcv[2048+c8+3];
      o1.x = a8[4] + pcv[c8+4] + pcv[1024+c8+4] + pcv[2048+c8+4];
      o1.y = a8[5] + pcv[c8+5] + pcv[1024+c8+5] + pcv[2048+c8+5];
      o1.z = a8[6] + pcv[c8+6] + pcv[1024+c8+6] + pcv[2048+c8+6];
      o1.w = a8[7] + pcv[c8+7] + pcv[1024+c8+7] + pcv[2048+c8+7];
      *(float4*)&ctxp[(size_t)bid * 1024 + c8] = o0;
      *(float4*)&ctxp[(size_t)bid * 1024 + c8 + 4] = o1;
    }
  }
}

// ---------------- combine tile partials -> xin[:, :1024]; gather emb -> xin[:, 1024:]
__global__ void k_attn_reduce(const float* __restrict__ ctxp, const float* __restrict__ stats,
                              const int* __restrict__ x, const float* __restrict__ emb,
                              float* __restrict__ xin) {
  __shared__ float ps[32];
  __shared__ float invs;
  const int b = blockIdx.x, t = threadIdx.x;
  if (t < 32) ps[t] = stats[b * 32 + t];
  __syncthreads();
  if (t == 0) {
    float s = 0.f;
    #pragma unroll
    for (int i = 0; i < 32; ++i) s += ps[i];
    invs = 1.f / s;
  }
  __syncthreads();
  const float inv = invs;
  #pragma unroll
  for (int i = 0; i < 4; ++i) {
    int c = t + i * 256;
    float a = 0.f;
    for (int chv = 0; chv < 32; ++chv)
      a += ctxp[((size_t)b * 32 + chv) * 1024 + c];
    xin[(size_t)b * 1280 + c] = a * inv;
  }
  xin[(size_t)b * 1280 + 1024 + t] = emb[(size_t)x[b] * 256 + t];
}

// ---------------- z_part = xin @ K  (dir x ksplit x jtile), f32
// double-buffered xl -> ONE barrier per 32-k chunk (was 2; 80 -> 41 barriers)
__global__ void k_lstm_gemm(const float* __restrict__ xin, const float* __restrict__ Kf,
                            const float* __restrict__ Kb, float* __restrict__ zpart) {
  __shared__ float xl[2][32][68];   // [buf][kk][b], padded
  const int t = threadIdx.x;
  const int bid = blockIdx.x;          // 2 dir * 64 jt * 2 ks = 256
  const int dir = bid >> 7;
  const int jt  = (bid >> 1) & 63;
  const int ks  = bid & 1;
  const float* K = dir ? Kb : Kf;
  const int j  = jt * 32 + (t & 31);
  const int tb = t >> 5;               // 8 groups of 8 b
  const int brow = t >> 2, kq = (t & 3) * 8;
  float acc[8] = {0,0,0,0,0,0,0,0};
  const int kbase = ks * 640;
  {  // prologue: stage chunk 0 into buf 0
    float4 x0 = *(const float4*)&xin[(size_t)brow * 1280 + kbase + kq];
    float4 x1 = *(const float4*)&xin[(size_t)brow * 1280 + kbase + kq + 4];
    xl[0][kq+0][brow]=x0.x; xl[0][kq+1][brow]=x0.y; xl[0][kq+2][brow]=x0.z; xl[0][kq+3][brow]=x0.w;
    xl[0][kq+4][brow]=x1.x; xl[0][kq+5][brow]=x1.y; xl[0][kq+6][brow]=x1.z; xl[0][kq+7][brow]=x1.w;
  }
  __syncthreads();
  for (int c = 0; c < 20; ++c) {
    const int cur = c & 1;
    if (c < 19) {   // stage chunk c+1 into other buffer (no barrier before use)
      const int k0 = kbase + (c + 1) * 32;
      float4 x0 = *(const float4*)&xin[(size_t)brow * 1280 + k0 + kq];
      float4 x1 = *(const float4*)&xin[(size_t)brow * 1280 + k0 + kq + 4];
      const int nb = cur ^ 1;
      xl[nb][kq+0][brow]=x0.x; xl[nb][kq+1][brow]=x0.y; xl[nb][kq+2][brow]=x0.z; xl[nb][kq+3][brow]=x0.w;
      xl[nb][kq+4][brow]=x1.x; xl[nb][kq+5][brow]=x1.y; xl[nb][kq+6][brow]=x1.z; xl[nb][kq+7][brow]=x1.w;
    }
    const float* Kp = K + (size_t)(kbase + c * 32) * 2048 + j;
    #pragma unroll 8
    for (int kk = 0; kk < 32; ++kk) {
      float wv = Kp[(size_t)kk * 2048];
      float4 v0 = *(const float4*)&xl[cur][kk][tb * 8];
      float4 v1 = *(const float4*)&xl[cur][kk][tb * 8 + 4];
      acc[0] += v0.x * wv; acc[1] += v0.y * wv; acc[2] += v0.z * wv; acc[3] += v0.w * wv;
      acc[4] += v1.x * wv; acc[5] += v1.y * wv; acc[6] += v1.z * wv; acc[7] += v1.w * wv;
    }
    __syncthreads();
  }
  float* zp = zpart + ((size_t)dir * 2 + ks) * 64 * 2048;
  #pragma unroll
  for (int i = 0; i < 8; ++i)
    zp[(size_t)(tb * 8 + i) * 2048 + j] = acc[i];
}

// ---------------- gates: c = sig(i)*tanh(g); h = sig(o)*tanh(c); also h -> hi/lo bf16
__global__ void k_gates(const float* __restrict__ zpart, const float* __restrict__ bfv,
                        const float* __restrict__ bbv, float* __restrict__ dout,
                        u16* __restrict__ hhl) {
  const int dir = blockIdx.x >> 6, b = blockIdx.x & 63, u = threadIdx.x;
  const float* bias = dir ? bbv : bfv;
  const float* z0 = zpart + ((size_t)dir * 2 + 0) * 131072 + (size_t)b * 2048;
  const float* z1 = zpart + ((size_t)dir * 2 + 1) * 131072 + (size_t)b * 2048;
  float zi = z0[u]        + z1[u]        + bias[u];
  float zg = z0[1024 + u] + z1[1024 + u] + bias[1024 + u];
  float zo = z0[1536 + u] + z1[1536 + u] + bias[1536 + u];
  float c = fast_sig(zi) * fast_tanh(zg);
  float h = fast_sig(zo) * fast_tanh(c);
  size_t base = 3200000u + (size_t)dir * 65536u;
  dout[base + (size_t)b * 512 + u] = h;
  dout[base + 32768u + (size_t)b * 512 + u] = c;
  u16 hi = f2bf(h);
  u16 lo = f2bf(h - bf2f(hi));
  hhl[(size_t)b * 1024 + dir * 512 + u] = hi;
  hhl[65536u + (size_t)b * 1024 + dir * 512 + u] = lo;
}

// ---------------- logits = [hf hb] @ fc_w + fc_b  via MFMA, fcw read DIRECTLY as f32
__global__ void __launch_bounds__(256)
k_fc_mfma(const float* __restrict__ fcw, const u16* __restrict__ hhl,
          const float* __restrict__ fcb, float* __restrict__ logits) {
  __shared__ float Bs[2][32 * 136];
  const int t = threadIdx.x;
  const int j0 = blockIdx.x * 128;
  const int l = t & 63, w = t >> 6;
  const int ln = l & 15, lg = l >> 4;
  const int srow = t >> 3, scol = (t & 7) * 16;
  const bool interior = (j0 + 128 <= 50000);

  f32x4 acc[4][2];
  #pragma unroll
  for (int im = 0; im < 4; ++im)
    #pragma unroll
    for (int nf = 0; nf < 2; ++nf) acc[im][nf] = f32x4{0.f, 0.f, 0.f, 0.f};

  float4 pre[4];
  {
    const float* src = fcw + (size_t)srow * 50000 + j0 + scol;
    if (interior) {
      #pragma unroll
      for (int q = 0; q < 4; ++q) pre[q] = *(const float4*)(src + q * 4);
    } else {
      #pragma unroll
      for (int q = 0; q < 4; ++q) {
        int jb = j0 + scol + q * 4;
        pre[q].x = (jb + 0 < 50000) ? src[q*4 + 0] : 0.f;
        pre[q].y = (jb + 1 < 50000) ? src[q*4 + 1] : 0.f;
        pre[q].z = (jb + 2 < 50000) ? src[q*4 + 2] : 0.f;
        pre[q].w = (jb + 3 < 50000) ? src[q*4 + 3] : 0.f;
      }
    }
    #pragma unroll
    for (int q = 0; q < 4; ++q)
      *(float4*)&Bs[0][srow * 136 + scol + q * 4] = pre[q];
  }
  __syncthreads();

  for (int ks = 0; ks < 32; ++ks) {
    const int cur = ks & 1;
    if (ks < 31) {
      const float* src = fcw + (size_t)(ks + 1) * 32 * 50000 + (size_t)srow * 50000 + j0 + scol;
      if (interior) {
        #pragma unroll
        for (int q = 0; q < 4; ++q) pre[q] = *(const float4*)(src + q * 4);
      } else {
        #pragma unroll
        for (int q = 0; q < 4; ++q) {
          int jb = j0 + scol + q * 4;
          pre[q].x = (jb + 0 < 50000) ? src[q*4 + 0] : 0.f;
          pre[q].y = (jb + 1 < 50000) ? src[q*4 + 1] : 0.f;
          pre[q].z = (jb + 2 < 50000) ? src[q*4 + 2] : 0.f;
          pre[q].w = (jb + 3 < 50000) ? src[q*4 + 3] : 0.f;
        }
      }
    }
    bf16x8 ahi[4], alo[4];
    #pragma unroll
    for (int im = 0; im < 4; ++im) {
      const u16* ha = hhl + (size_t)(im * 16 + ln) * 1024 + ks * 32 + lg * 8;
      ahi[im] = *(const bf16x8*)(ha);
      alo[im] = *(const bf16x8*)(ha + 65536);
    }
    bf16x8 bfr[2];
    #pragma unroll
    for (int nf = 0; nf < 2; ++nf) {
      u16x8 pv;
      #pragma unroll
      for (int i = 0; i < 8; ++i)
        pv[i] = f2bf(Bs[cur][(lg * 8 + i) * 136 + w * 32 + nf * 16 + ln]);
      bfr[nf] = *(bf16x8*)&pv;
    }
    #pragma unroll
    for (int im = 0; im < 4; ++im)
      #pragma unroll
      for (int nf = 0; nf < 2; ++nf) {
        acc[im][nf] = __builtin_amdgcn_mfma_f32_16x16x32_bf16(alo[im], bfr[nf], acc[im][nf], 0, 0, 0);
        acc[im][nf] = __builtin_amdgcn_mfma_f32_16x16x32_bf16(ahi[im], bfr[nf], acc[im][nf], 0, 0, 0);
      }
    if (ks < 31) {
      #pragma unroll
      for (int q = 0; q < 4; ++q)
        *(float4*)&Bs[cur ^ 1][srow * 136 + scol + q * 4] = pre[q];
    }
    __syncthreads();
  }

  #pragma unroll
  for (int nf = 0; nf < 2; ++nf) {
    int c = j0 + w * 32 + nf * 16 + ln;
    if (c < 50000) {
      float fb = fcb[c];
      #pragma unroll
      for (int im = 0; im < 4; ++im)
        #pragma unroll
        for (int r = 0; r < 4; ++r) {
          int row = im * 16 + lg * 4 + r;
          logits[(size_t)row * 50000 + c] = acc[im][nf][r] + fb;
        }
    }
  }
}

// ---------------- fallback f32 fc (used when ws too small for scratch arena)
__global__ void __launch_bounds__(256)
k_fc_f32(const float* __restrict__ dout_ro, const float* __restrict__ fcw,
         const float* __restrict__ fcb, float* __restrict__ logits) {
  __shared__ float ol[64][68];
  __shared__ float wl[64][132];
  const int t = threadIdx.x;
  const int j0 = blockIdx.x * 128;
  const int tb = t >> 5, tj = t & 31;
  const float* hf = dout_ro + 3200000u;
  const float* hb = dout_ro + 3200000u + 65536u;
  float acc[8][4];
  #pragma unroll
  for (int bi = 0; bi < 8; ++bi)
    #pragma unroll
    for (int ji = 0; ji < 4; ++ji) acc[bi][ji] = 0.f;

  for (int k0 = 0; k0 < 1024; k0 += 64) {
    __syncthreads();
    {
      int bb = t >> 2, kq = (t & 3) * 16;
      const float* src = (k0 < 512) ? (hf + (size_t)bb * 512 + k0 + kq)
                                    : (hb + (size_t)bb * 512 + (k0 - 512) + kq);
      #pragma unroll
      for (int i = 0; i < 4; ++i) {
        float4 v = *(const float4*)(src + i * 4);
        ol[kq + i*4 + 0][bb] = v.x;
        ol[kq + i*4 + 1][bb] = v.y;
        ol[kq + i*4 + 2][bb] = v.z;
        ol[kq + i*4 + 3][bb] = v.w;
      }
    }
    {
      int kk = t >> 2, jh = (t & 3) * 32;
      const float* wsrc = fcw + (size_t)(k0 + kk) * 50000 + j0 + jh;
      #pragma unroll
      for (int i = 0; i < 8; ++i) {
        int j = j0 + jh + i * 4;
        float4 v;
        if (j + 3 < 50000) {
          v = *(const float4*)(wsrc + i * 4);
        } else {
          v.x = (j + 0 < 50000) ? wsrc[i*4 + 0] : 0.f;
          v.y = (j + 1 < 50000) ? wsrc[i*4 + 1] : 0.f;
          v.z = (j + 2 < 50000) ? wsrc[i*4 + 2] : 0.f;
          v.w = 0.f;
        }
        *(float4*)&wl[kk][jh + i * 4] = v;
      }
    }
    __syncthreads();
    #pragma unroll 4
    for (int kk = 0; kk < 64; ++kk) {
      float4 wv = *(const float4*)&wl[kk][tj * 4];
      float4 q0 = *(const float4*)&ol[kk][tb * 8];
      float4 q1 = *(const float4*)&ol[kk][tb * 8 + 4];
      float obv[8] = {q0.x, q0.y, q0.z, q0.w, q1.x, q1.y, q1.z, q1.w};
      #pragma unroll
      for (int bi = 0; bi < 8; ++bi) {
        acc[bi][0] += obv[bi] * wv.x;
        acc[bi][1] += obv[bi] * wv.y;
        acc[bi][2] += obv[bi] * wv.z;
        acc[bi][3] += obv[bi] * wv.w;
      }
    }
  }

  const int j = j0 + tj * 4;
  if (j + 3 < 50000) {
    float4 fb = *(const float4*)(fcb + j);
    #pragma unroll
    for (int bi = 0; bi < 8; ++bi) {
      float4 r;
      r.x = acc[bi][0] + fb.x; r.y = acc[bi][1] + fb.y;
      r.z = acc[bi][2] + fb.z; r.w = acc[bi][3] + fb.w;
      *(float4*)&logits[(size_t)(tb * 8 + bi) * 50000 + j] = r;
    }
  } else {
    for (int ji = 0; ji < 4; ++ji) {
      if (j + ji < 50000) {
        float fb = fcb[j + ji];
        for (int bi = 0; bi < 8; ++bi)
          logits[(size_t)(tb * 8 + bi) * 50000 + j + ji] = acc[bi][ji] + fb;
      }
    }
  }
}

extern "C" void kernel_launch(void* const* d_in, const int* in_sizes, int n_in,
                              void* d_out, int out_size, void* d_ws, size_t ws_size,
                              hipStream_t stream) {
  const int*   x    = (const int*)  d_in[0];
  const float* cfwd = (const float*)d_in[1];
  const float* cbwd = (const float*)d_in[2];
  const float* enc  = (const float*)d_in[3];
  const float* emb  = (const float*)d_in[4];
  const float* W1w  = (const float*)d_in[5];
  const float* W1b  = (const float*)d_in[6];
  const float* W2w  = (const float*)d_in[7];
  const float* W2b  = (const float*)d_in[8];
  const float* W3w  = (const float*)d_in[9];
  const float* W3b  = (const float*)d_in[10];
  const float* Vw   = (const float*)d_in[11];
  const float* Vb   = (const float*)d_in[12];
  const float* Kf   = (const float*)d_in[13];
  const float* bfv  = (const float*)d_in[14];
  const float* Kb   = (const float*)d_in[15];
  const float* bbv  = (const float*)d_in[16];
  const float* fcw  = (const float*)d_in[17];
  const float* fcb  = (const float*)d_in[18];
  float* out = (float*)d_out;

  const bool haveWs = (ws_size >= SCRATCH_BYTES);
  float* S = haveWs ? (float*)d_ws : out;   // fallback carve ends 3065856 < 3200000
  u16*   w1p   = (u16*)S;
  float* hpb   = S + OF_HPB;
  float* ctxp  = S + OF_CTXP;
  float* stats = S + OF_STATS;
  float* xin   = S + OF_XIN;
  float* zpart = S + OF_ZPART;
  u16*   hhl   = (u16*)(S + OF_HHL);

  k_prep<<<128, 256, 0, stream>>>(W1w, w1p, cfwd, cbwd, W2w, W2b, W3w, W3b, W1b, hpb);
  k_attn<<<2048, 512, 0, stream>>>(enc, w1p, hpb, Vw, Vb, ctxp, stats);
  k_attn_reduce<<<64, 256, 0, stream>>>(ctxp, stats, x, emb, xin);
  k_lstm_gemm<<<256, 256, 0, stream>>>(xin, Kf, Kb, zpart);
  k_gates<<<128, 512, 0, stream>>>(zpart, bfv, bbv, out, hhl);
  if (haveWs) k_fc_mfma<<<392, 256, 0, stream>>>(fcw, hhl, fcb, out);
  else        k_fc_f32<<<391, 256, 0, stream>>>(out, fcw, fcb, out);
}

// Round 17
// 508.077 us; speedup vs baseline: 1.0160x; 1.0160x over previous
//
#include <hip/hip_runtime.h>

using u16 = unsigned short;
typedef float f32x4 __attribute__((ext_vector_type(4)));
typedef float f32x16 __attribute__((ext_vector_type(16)));
typedef __bf16 bf16x8 __attribute__((ext_vector_type(8)));
typedef u16 u16x8 __attribute__((ext_vector_type(8)));
typedef u16 u16x4 __attribute__((ext_vector_type(4)));

// dims: B=64, S=2048, ENC=1024, U=512, E=256, V=50000, IN=1280
// scratch layout (float units)
static constexpr int OF_HPB   = 262144;    // w1p: 512K u16
static constexpr int OF_CTXP  = 294912;    // hpb: 64*512
static constexpr int OF_STATS = 2392064;   // ctxp: 2048*1024 f32
static constexpr int OF_XIN   = 2394112;   // stats: 2048
static constexpr int OF_ZPART = 2476032;   // xin: 64*1280
static constexpr int OF_HHL   = 3000320;   // zpart: 4*64*2048; hhl: 2*64*1024 u16
static constexpr size_t SCRATCH_FLOATS = 3065856;
static constexpr size_t SCRATCH_BYTES  = SCRATCH_FLOATS * 4ull;   // ~12.3 MB

__device__ __forceinline__ u16 f2bf(float f) {
  unsigned u = __float_as_uint(f);
  u += 0x7FFFu + ((u >> 16) & 1u);   // RNE; inputs finite
  return (u16)(u >> 16);
}
__device__ __forceinline__ float bf2f(u16 u) {
  return __uint_as_float((unsigned)u << 16);
}
__device__ __forceinline__ float fast_tanh(float x) {
  x = fminf(fmaxf(x, -20.f), 20.f);
  float e = __expf(2.f * x);
  return (e - 1.f) / (e + 1.f);
}
__device__ __forceinline__ float fast_sig(float x) { return 1.f / (1.f + __expf(-x)); }

// ---------------- merged prep: blocks 0..63 pack W1 -> w1p; blocks 64..127 compute hpb
// w1p[ks16*8192 + (ug*64 + l)*8 + e] = W1[ks16*16 + (l>>5)*8 + e][ug*32 + (l&31)]
__global__ void k_prep(const float* __restrict__ W1w, u16* __restrict__ w1p,
                       const float* __restrict__ cf, const float* __restrict__ cb,
                       const float* __restrict__ W2w, const float* __restrict__ W2b,
                       const float* __restrict__ W3w, const float* __restrict__ W3b,
                       const float* __restrict__ W1b, float* __restrict__ hpb) {
  __shared__ float tile[16][516];
  const int t = threadIdx.x;
  if (blockIdx.x < 64) {
    const int ks = blockIdx.x;
    {
      int kk = t >> 4, u0 = (t & 15) * 32;
      const float* src = W1w + (size_t)(ks * 16 + kk) * 512 + u0;
      #pragma unroll
      for (int i = 0; i < 8; ++i)
        *(float4*)&tile[kk][u0 + i * 4] = *(const float4*)(src + i * 4);
    }
    __syncthreads();
    #pragma unroll
    for (int q = 0; q < 4; ++q) {
      int c = t + q * 256;              // chunk 0..1023
      int ug = c >> 6, l = c & 63;
      int u = ug * 32 + (l & 31), koct = l >> 5;
      u16x8 p;
      #pragma unroll
      for (int e = 0; e < 8; ++e) p[e] = f2bf(tile[koct * 8 + e][u]);
      *(u16x8*)(w1p + (size_t)ks * 8192 + (size_t)c * 8) = p;
    }
  } else {
    float* cfl = &tile[0][0];
    float* cbl = &tile[0][0] + 512;
    const int b = blockIdx.x - 64;
    cfl[t] = cf[(size_t)b * 512 + t];       cfl[t + 256] = cf[(size_t)b * 512 + t + 256];
    cbl[t] = cb[(size_t)b * 512 + t];       cbl[t + 256] = cb[(size_t)b * 512 + t + 256];
    __syncthreads();
    const int u1 = t, u2 = t + 256;
    float a1 = W2b[u1] + W3b[u1] + W1b[u1];
    float a2 = W2b[u2] + W3b[u2] + W1b[u2];
    for (int k = 0; k < 512; ++k) {
      float c1 = cfl[k], c2 = cbl[k];
      const float* r2 = W2w + (size_t)k * 512;
      const float* r3 = W3w + (size_t)k * 512;
      a1 += c1 * r2[u1] + c2 * r3[u1];
      a2 += c1 * r2[u2] + c2 * r3[u2];
    }
    hpb[(size_t)b * 512 + u1] = a1;
    hpb[(size_t)b * 512 + u2] = a2;
  }
}

// ---------------- fused attention v10: r15 skeleton with macro-BK=128 (8 barriers,
// was 16). 2048 blocks = 64 b x 32 tiles (64 rows). 512 thr = 8 waves, wave tile
// 64x64 (acc[2][2] = 64 AGPR). Per barrier: 32 MFMA + 16 ds_read_b128 / wave.
// A prefetch 1 macro (16 f32 regs); B direct per k-step (L2-hot w1p).
// launch_bounds(512,2): <=128 VGPR (no spill; combined w/ 64 AGPR -> 2 blocks/CU
// = 4 waves/SIMD, r15's proven-saturated occupancy). LDS 33KB.
__global__ void __launch_bounds__(512, 2)
k_attn(const float* __restrict__ enc, const u16* __restrict__ w1p,
       const float* __restrict__ hpb, const float* __restrict__ Vw,
       const float* __restrict__ Vb, float* __restrict__ ctxp,
       float* __restrict__ stats) {
  __shared__ __align__(16) u16 smem[16512];   // A dbuf 2x8256 u16 (33KB); epi 3712 f32

  const int t = threadIdx.x;
  const int bid = blockIdx.x;
  const int b = bid >> 5, tile = bid & 31;
  const size_t row0 = (size_t)b * 2048 + (size_t)tile * 64;

  const int l = t & 63, wv = t >> 6;   // 8 waves; wave wv: rows 0..63 x u [wv*64,+64)

  const u16* bbase = w1p + (size_t)(wv * 2) * 512 + (size_t)l * 8;  // + ks*8192; b1=+512

  // staging: t -> row sr(64), ksl sq8(8) (16 consecutive k); 4 float4 -> 2 u16x8
  const int sr = t >> 3, sq8 = t & 7;
  const float* a_src = enc + (row0 + sr) * 1024 + sq8 * 16;   // + km*128
  const int a_dst = sq8 * 1032 + (sr >> 5) * 512 + (sr & 31) * 8;  // koct0; koct1 = +256

  f32x16 acc00, acc01, acc10, acc11;
  #pragma unroll
  for (int i = 0; i < 16; ++i) { acc00[i]=0.f; acc01[i]=0.f; acc10[i]=0.f; acc11[i]=0.f; }

  float4 p0, p1, p2, p3;
  {  // prologue: stage macro0 directly; macro1 loads in flight
    float4 v0 = *(const float4*)(a_src);
    float4 v1 = *(const float4*)(a_src + 4);
    float4 v2 = *(const float4*)(a_src + 8);
    float4 v3 = *(const float4*)(a_src + 12);
    u16x8 pka, pkb;
    pka[0]=f2bf(v0.x); pka[1]=f2bf(v0.y); pka[2]=f2bf(v0.z); pka[3]=f2bf(v0.w);
    pka[4]=f2bf(v1.x); pka[5]=f2bf(v1.y); pka[6]=f2bf(v1.z); pka[7]=f2bf(v1.w);
    pkb[0]=f2bf(v2.x); pkb[1]=f2bf(v2.y); pkb[2]=f2bf(v2.z); pkb[3]=f2bf(v2.w);
    pkb[4]=f2bf(v3.x); pkb[5]=f2bf(v3.y); pkb[6]=f2bf(v3.z); pkb[7]=f2bf(v3.w);
    *(u16x8*)(smem + a_dst) = pka;
    *(u16x8*)(smem + a_dst + 256) = pkb;
    p0 = *(const float4*)(a_src + 128);
    p1 = *(const float4*)(a_src + 132);
    p2 = *(const float4*)(a_src + 136);
    p3 = *(const float4*)(a_src + 140);
  }
  asm volatile("s_waitcnt lgkmcnt(0)" ::: "memory");
  __builtin_amdgcn_s_barrier();
  __builtin_amdgcn_sched_barrier(0);

  for (int km = 0; km < 8; ++km) {
    const int cur = km & 1;
    if (km < 7) {                 // stage A(km+1) (regs loaded last iter)
      u16x8 pka, pkb;
      pka[0]=f2bf(p0.x); pka[1]=f2bf(p0.y); pka[2]=f2bf(p0.z); pka[3]=f2bf(p0.w);
      pka[4]=f2bf(p1.x); pka[5]=f2bf(p1.y); pka[6]=f2bf(p1.z); pka[7]=f2bf(p1.w);
      pkb[0]=f2bf(p2.x); pkb[1]=f2bf(p2.y); pkb[2]=f2bf(p2.z); pkb[3]=f2bf(p2.w);
      pkb[4]=f2bf(p3.x); pkb[5]=f2bf(p3.y); pkb[6]=f2bf(p3.z); pkb[7]=f2bf(p3.w);
      u16* d = smem + (cur ^ 1) * 8256 + a_dst;
      *(u16x8*)(d) = pka;
      *(u16x8*)(d + 256) = pkb;
      if (km < 6) {               // issue A(km+2)
        const float* sp = a_src + (km + 2) * 128;
        p0 = *(const float4*)(sp);
        p1 = *(const float4*)(sp + 4);
        p2 = *(const float4*)(sp + 8);
        p3 = *(const float4*)(sp + 12);
      }
    }
    const u16* Ac = smem + cur * 8256;
    #pragma unroll
    for (int m = 0; m < 8; ++m) {
      bf16x8 a0 = *(const bf16x8*)(Ac + m * 1032 + l * 8);          // rows 0..31
      bf16x8 a1 = *(const bf16x8*)(Ac + m * 1032 + 512 + l * 8);    // rows 32..63
      const u16* bp = bbase + (size_t)(km * 8 + m) * 8192;
      bf16x8 b0 = *(const bf16x8*)(bp);           // u [wv*64, +32)
      bf16x8 b1 = *(const bf16x8*)(bp + 512);     // u [wv*64+32, +32)
      acc00 = __builtin_amdgcn_mfma_f32_32x32x16_bf16(a0, b0, acc00, 0, 0, 0);
      acc01 = __builtin_amdgcn_mfma_f32_32x32x16_bf16(a0, b1, acc01, 0, 0, 0);
      acc10 = __builtin_amdgcn_mfma_f32_32x32x16_bf16(a1, b0, acc10, 0, 0, 0);
      acc11 = __builtin_amdgcn_mfma_f32_32x32x16_bf16(a1, b1, acc11, 0, 0, 0);
    }
    asm volatile("s_waitcnt lgkmcnt(0)" ::: "memory");
    __builtin_amdgcn_s_barrier();
    __builtin_amdgcn_sched_barrier(0);
  }

  // ---- epilogue (smem reused as f32): score -> exp -> stats
  float* fsm = (float*)smem;
  float* red = fsm;            // [64][9]
  float* scv = fsm + 576;      // [64]
  float* pcv = fsm + 640;      // [3][1024]

  {
    const int lu = l & 31;
    const float vw0 = Vw[wv * 64 + lu];
    const float vw1 = Vw[wv * 64 + 32 + lu];
    const float hp0 = hpb[(size_t)b * 512 + wv * 64 + lu];
    const float hp1 = hpb[(size_t)b * 512 + wv * 64 + 32 + lu];
    const int hi4 = (l >> 5) * 4;
    const bool writer = (lu == 0);
    // D mapping (32x32): col=lane&31 (u), row=(r&3)+8*(r>>2)+4*(lane>>5) (s)
    #pragma unroll
    for (int mi = 0; mi < 2; ++mi) {
      #pragma unroll
      for (int r = 0; r < 16; ++r) {
        float s = vw0 * fast_tanh((mi ? acc10[r] : acc00[r]) + hp0)
                + vw1 * fast_tanh((mi ? acc11[r] : acc01[r]) + hp1);
        s += __shfl_xor(s, 1);
        s += __shfl_xor(s, 2);
        s += __shfl_xor(s, 4);
        s += __shfl_xor(s, 8);
        s += __shfl_xor(s, 16);
        if (writer) {
          int row = mi * 32 + (r & 3) + 8 * (r >> 2) + hi4;
          red[row * 9 + wv] = s;
        }
      }
    }
  }
  __syncthreads();
  if (t < 64) {
    float s = Vb[0];
    #pragma unroll
    for (int wq = 0; wq < 8; ++wq) s += red[t * 9 + wq];
    float e = __expf(s);   // |score| bounded (~||Vw||_1): f32-safe without max-sub
    scv[t] = e;
    float p = e;
    p += __shfl_xor(p, 1);  p += __shfl_xor(p, 2);  p += __shfl_xor(p, 4);
    p += __shfl_xor(p, 8);  p += __shfl_xor(p, 16); p += __shfl_xor(p, 32);
    if (t == 0) stats[bid] = p;
  }
  __syncthreads();

  // ---- tail-PV: unnormalized partial ctx from own (L3-hot) f32 enc tile
  {
    const int c8 = (t & 127) * 8;
    const int rq = t >> 7;               // 0..3 -> rows rq*16..+16
    const float* ep = enc + (row0 + rq * 16) * 1024 + c8;
    float a8[8] = {0.f,0.f,0.f,0.f,0.f,0.f,0.f,0.f};
    #pragma unroll 4
    for (int r = 0; r < 16; ++r) {
      float4 v0 = *(const float4*)(ep + (size_t)r * 1024);
      float4 v1 = *(const float4*)(ep + (size_t)r * 1024 + 4);
      float sc = scv[rq * 16 + r];
      a8[0] += sc * v0.x; a8[1] += sc * v0.y; a8[2] += sc * v0.z; a8[3] += sc * v0.w;
      a8[4] += sc * v1.x; a8[5] += sc * v1.y; a8[6] += sc * v1.z; a8[7] += sc * v1.w;
    }
    if (rq) {
      float4 s0 = {a8[0], a8[1], a8[2], a8[3]};
      float4 s1 = {a8[4], a8[5], a8[6], a8[7]};
      *(float4*)&pcv[(rq - 1) * 1024 + c8] = s0;
      *(float4*)&pcv[(rq - 1) * 1024 + c8 + 4] = s1;
    }
    __syncthreads();
    if (rq == 0) {
      float4 o0, o1;
      o0.x = a8[0] + pcv[c8+0] + pcv[1024+c8+0] + pcv[2048+c8+0];
      o0.y = a8[1] + pcv[c8+1] + pcv[1024+c8+1] + pcv[2048+c8+1];
      o0.z = a8[2] + pcv[c8+2] + pcv[1024+c8+2] + pcv[2048+c8+2];
      o0.w = a8[3] + pcv[c8+3] + pcv[1024+c8+3] + pcv[2048+c8+3];
      o1.x = a8[4] + pcv[c8+4] + pcv[1024+c8+4] + pcv[2048+c8+4];
      o1.y = a8[5] + pcv[c8+5] + pcv[1024+c8+5] + pcv[2048+c8+5];
      o1.z = a8[6] + pcv[c8+6] + pcv[1024+c8+6] + pcv[2048+c8+6];
      o1.w = a8[7] + pcv[c8+7] + pcv[1024+c8+7] + pcv[2048+c8+7];
      *(float4*)&ctxp[(size_t)bid * 1024 + c8] = o0;
      *(float4*)&ctxp[(size_t)bid * 1024 + c8 + 4] = o1;
    }
  }
}

// ---------------- combine tile partials -> xin[:, :1024]; gather emb -> xin[:, 1024:]
__global__ void k_attn_reduce(const float* __restrict__ ctxp, const float* __restrict__ stats,
                              const int* __restrict__ x, const float* __restrict__ emb,
                              float* __restrict__ xin) {
  __shared__ float ps[32];
  __shared__ float invs;
  const int b = blockIdx.x, t = threadIdx.x;
  if (t < 32) ps[t] = stats[b * 32 + t];
  __syncthreads();
  if (t == 0) {
    float s = 0.f;
    #pragma unroll
    for (int i = 0; i < 32; ++i) s += ps[i];
    invs = 1.f / s;
  }
  __syncthreads();
  const float inv = invs;
  #pragma unroll
  for (int i = 0; i < 4; ++i) {
    int c = t + i * 256;
    float a = 0.f;
    for (int chv = 0; chv < 32; ++chv)
      a += ctxp[((size_t)b * 32 + chv) * 1024 + c];
    xin[(size_t)b * 1280 + c] = a * inv;
  }
  xin[(size_t)b * 1280 + 1024 + t] = emb[(size_t)x[b] * 256 + t];
}

// ---------------- z_part = xin @ K  (dir x ksplit x jtile), f32  [r10-proven version]
__global__ void k_lstm_gemm(const float* __restrict__ xin, const float* __restrict__ Kf,
                            const float* __restrict__ Kb, float* __restrict__ zpart) {
  __shared__ float xl[32][68];   // [kk][b], padded
  const int t = threadIdx.x;
  const int bid = blockIdx.x;          // 2 dir * 64 jt * 2 ks = 256
  const int dir = bid >> 7;
  const int jt  = (bid >> 1) & 63;
  const int ks  = bid & 1;
  const float* K = dir ? Kb : Kf;
  const int j  = jt * 32 + (t & 31);
  const int tb = t >> 5;               // 8 groups of 8 b
  const int brow = t >> 2, kq = (t & 3) * 8;
  float acc[8] = {0,0,0,0,0,0,0,0};
  for (int k0 = ks * 640; k0 < ks * 640 + 640; k0 += 32) {
    float4 x0 = *(const float4*)&xin[(size_t)brow * 1280 + k0 + kq];
    float4 x1 = *(const float4*)&xin[(size_t)brow * 1280 + k0 + kq + 4];
    __syncthreads();
    xl[kq+0][brow]=x0.x; xl[kq+1][brow]=x0.y; xl[kq+2][brow]=x0.z; xl[kq+3][brow]=x0.w;
    xl[kq+4][brow]=x1.x; xl[kq+5][brow]=x1.y; xl[kq+6][brow]=x1.z; xl[kq+7][brow]=x1.w;
    __syncthreads();
    const float* Kp = K + (size_t)k0 * 2048 + j;
    #pragma unroll 8
    for (int kk = 0; kk < 32; ++kk) {
      float wv = Kp[(size_t)kk * 2048];
      float4 v0 = *(const float4*)&xl[kk][tb * 8];
      float4 v1 = *(const float4*)&xl[kk][tb * 8 + 4];
      acc[0] += v0.x * wv; acc[1] += v0.y * wv; acc[2] += v0.z * wv; acc[3] += v0.w * wv;
      acc[4] += v1.x * wv; acc[5] += v1.y * wv; acc[6] += v1.z * wv; acc[7] += v1.w * wv;
    }
  }
  float* zp = zpart + ((size_t)dir * 2 + ks) * 64 * 2048;
  #pragma unroll
  for (int i = 0; i < 8; ++i)
    zp[(size_t)(tb * 8 + i) * 2048 + j] = acc[i];
}

// ---------------- gates: c = sig(i)*tanh(g); h = sig(o)*tanh(c); also h -> hi/lo bf16
__global__ void k_gates(const float* __restrict__ zpart, const float* __restrict__ bfv,
                        const float* __restrict__ bbv, float* __restrict__ dout,
                        u16* __restrict__ hhl) {
  const int dir = blockIdx.x >> 6, b = blockIdx.x & 63, u = threadIdx.x;
  const float* bias = dir ? bbv : bfv;
  const float* z0 = zpart + ((size_t)dir * 2 + 0) * 131072 + (size_t)b * 2048;
  const float* z1 = zpart + ((size_t)dir * 2 + 1) * 131072 + (size_t)b * 2048;
  float zi = z0[u]        + z1[u]        + bias[u];
  float zg = z0[1024 + u] + z1[1024 + u] + bias[1024 + u];
  float zo = z0[1536 + u] + z1[1536 + u] + bias[1536 + u];
  float c = fast_sig(zi) * fast_tanh(zg);
  float h = fast_sig(zo) * fast_tanh(c);
  size_t base = 3200000u + (size_t)dir * 65536u;
  dout[base + (size_t)b * 512 + u] = h;
  dout[base + 32768u + (size_t)b * 512 + u] = c;
  u16 hi = f2bf(h);
  u16 lo = f2bf(h - bf2f(hi));
  hhl[(size_t)b * 1024 + dir * 512 + u] = hi;
  hhl[65536u + (size_t)b * 1024 + dir * 512 + u] = lo;
}

// ---------------- logits = [hf hb] @ fc_w + fc_b  via MFMA, fcw read DIRECTLY as f32
__global__ void __launch_bounds__(256)
k_fc_mfma(const float* __restrict__ fcw, const u16* __restrict__ hhl,
          const float* __restrict__ fcb, float* __restrict__ logits) {
  __shared__ float Bs[2][32 * 136];
  const int t = threadIdx.x;
  const int j0 = blockIdx.x * 128;
  const int l = t & 63, w = t >> 6;
  const int ln = l & 15, lg = l >> 4;
  const int srow = t >> 3, scol = (t & 7) * 16;
  const bool interior = (j0 + 128 <= 50000);

  f32x4 acc[4][2];
  #pragma unroll
  for (int im = 0; im < 4; ++im)
    #pragma unroll
    for (int nf = 0; nf < 2; ++nf) acc[im][nf] = f32x4{0.f, 0.f, 0.f, 0.f};

  float4 pre[4];
  {
    const float* src = fcw + (size_t)srow * 50000 + j0 + scol;
    if (interior) {
      #pragma unroll
      for (int q = 0; q < 4; ++q) pre[q] = *(const float4*)(src + q * 4);
    } else {
      #pragma unroll
      for (int q = 0; q < 4; ++q) {
        int jb = j0 + scol + q * 4;
        pre[q].x = (jb + 0 < 50000) ? src[q*4 + 0] : 0.f;
        pre[q].y = (jb + 1 < 50000) ? src[q*4 + 1] : 0.f;
        pre[q].z = (jb + 2 < 50000) ? src[q*4 + 2] : 0.f;
        pre[q].w = (jb + 3 < 50000) ? src[q*4 + 3] : 0.f;
      }
    }
    #pragma unroll
    for (int q = 0; q < 4; ++q)
      *(float4*)&Bs[0][srow * 136 + scol + q * 4] = pre[q];
  }
  __syncthreads();

  for (int ks = 0; ks < 32; ++ks) {
    const int cur = ks & 1;
    if (ks < 31) {
      const float* src = fcw + (size_t)(ks + 1) * 32 * 50000 + (size_t)srow * 50000 + j0 + scol;
      if (interior) {
        #pragma unroll
        for (int q = 0; q < 4; ++q) pre[q] = *(const float4*)(src + q * 4);
      } else {
        #pragma unroll
        for (int q = 0; q < 4; ++q) {
          int jb = j0 + scol + q * 4;
          pre[q].x = (jb + 0 < 50000) ? src[q*4 + 0] : 0.f;
          pre[q].y = (jb + 1 < 50000) ? src[q*4 + 1] : 0.f;
          pre[q].z = (jb + 2 < 50000) ? src[q*4 + 2] : 0.f;
          pre[q].w = (jb + 3 < 50000) ? src[q*4 + 3] : 0.f;
        }
      }
    }
    bf16x8 ahi[4], alo[4];
    #pragma unroll
    for (int im = 0; im < 4; ++im) {
      const u16* ha = hhl + (size_t)(im * 16 + ln) * 1024 + ks * 32 + lg * 8;
      ahi[im] = *(const bf16x8*)(ha);
      alo[im] = *(const bf16x8*)(ha + 65536);
    }
    bf16x8 bfr[2];
    #pragma unroll
    for (int nf = 0; nf < 2; ++nf) {
      u16x8 pv;
      #pragma unroll
      for (int i = 0; i < 8; ++i)
        pv[i] = f2bf(Bs[cur][(lg * 8 + i) * 136 + w * 32 + nf * 16 + ln]);
      bfr[nf] = *(bf16x8*)&pv;
    }
    #pragma unroll
    for (int im = 0; im < 4; ++im)
      #pragma unroll
      for (int nf = 0; nf < 2; ++nf) {
        acc[im][nf] = __builtin_amdgcn_mfma_f32_16x16x32_bf16(alo[im], bfr[nf], acc[im][nf], 0, 0, 0);
        acc[im][nf] = __builtin_amdgcn_mfma_f32_16x16x32_bf16(ahi[im], bfr[nf], acc[im][nf], 0, 0, 0);
      }
    if (ks < 31) {
      #pragma unroll
      for (int q = 0; q < 4; ++q)
        *(float4*)&Bs[cur ^ 1][srow * 136 + scol + q * 4] = pre[q];
    }
    __syncthreads();
  }

  #pragma unroll
  for (int nf = 0; nf < 2; ++nf) {
    int c = j0 + w * 32 + nf * 16 + ln;
    if (c < 50000) {
      float fb = fcb[c];
      #pragma unroll
      for (int im = 0; im < 4; ++im)
        #pragma unroll
        for (int r = 0; r < 4; ++r) {
          int row = im * 16 + lg * 4 + r;
          logits[(size_t)row * 50000 + c] = acc[im][nf][r] + fb;
        }
    }
  }
}

// ---------------- fallback f32 fc (used when ws too small for scratch arena)
__global__ void __launch_bounds__(256)
k_fc_f32(const float* __restrict__ dout_ro, const float* __restrict__ fcw,
         const float* __restrict__ fcb, float* __restrict__ logits) {
  __shared__ float ol[64][68];
  __shared__ float wl[64][132];
  const int t = threadIdx.x;
  const int j0 = blockIdx.x * 128;
  const int tb = t >> 5, tj = t & 31;
  const float* hf = dout_ro + 3200000u;
  const float* hb = dout_ro + 3200000u + 65536u;
  float acc[8][4];
  #pragma unroll
  for (int bi = 0; bi < 8; ++bi)
    #pragma unroll
    for (int ji = 0; ji < 4; ++ji) acc[bi][ji] = 0.f;

  for (int k0 = 0; k0 < 1024; k0 += 64) {
    __syncthreads();
    {
      int bb = t >> 2, kq = (t & 3) * 16;
      const float* src = (k0 < 512) ? (hf + (size_t)bb * 512 + k0 + kq)
                                    : (hb + (size_t)bb * 512 + (k0 - 512) + kq);
      #pragma unroll
      for (int i = 0; i < 4; ++i) {
        float4 v = *(const float4*)(src + i * 4);
        ol[kq + i*4 + 0][bb] = v.x;
        ol[kq + i*4 + 1][bb] = v.y;
        ol[kq + i*4 + 2][bb] = v.z;
        ol[kq + i*4 + 3][bb] = v.w;
      }
    }
    {
      int kk = t >> 2, jh = (t & 3) * 32;
      const float* wsrc = fcw + (size_t)(k0 + kk) * 50000 + j0 + jh;
      #pragma unroll
      for (int i = 0; i < 8; ++i) {
        int j = j0 + jh + i * 4;
        float4 v;
        if (j + 3 < 50000) {
          v = *(const float4*)(wsrc + i * 4);
        } else {
          v.x = (j + 0 < 50000) ? wsrc[i*4 + 0] : 0.f;
          v.y = (j + 1 < 50000) ? wsrc[i*4 + 1] : 0.f;
          v.z = (j + 2 < 50000) ? wsrc[i*4 + 2] : 0.f;
          v.w = 0.f;
        }
        *(float4*)&wl[kk][jh + i * 4] = v;
      }
    }
    __syncthreads();
    #pragma unroll 4
    for (int kk = 0; kk < 64; ++kk) {
      float4 wv = *(const float4*)&wl[kk][tj * 4];
      float4 q0 = *(const float4*)&ol[kk][tb * 8];
      float4 q1 = *(const float4*)&ol[kk][tb * 8 + 4];
      float obv[8] = {q0.x, q0.y, q0.z, q0.w, q1.x, q1.y, q1.z, q1.w};
      #pragma unroll
      for (int bi = 0; bi < 8; ++bi) {
        acc[bi][0] += obv[bi] * wv.x;
        acc[bi][1] += obv[bi] * wv.y;
        acc[bi][2] += obv[bi] * wv.z;
        acc[bi][3] += obv[bi] * wv.w;
      }
    }
  }

  const int j = j0 + tj * 4;
  if (j + 3 < 50000) {
    float4 fb = *(const float4*)(fcb + j);
    #pragma unroll
    for (int bi = 0; bi < 8; ++bi) {
      float4 r;
      r.x = acc[bi][0] + fb.x; r.y = acc[bi][1] + fb.y;
      r.z = acc[bi][2] + fb.z; r.w = acc[bi][3] + fb.w;
      *(float4*)&logits[(size_t)(tb * 8 + bi) * 50000 + j] = r;
    }
  } else {
    for (int ji = 0; ji < 4; ++ji) {
      if (j + ji < 50000) {
        float fb = fcb[j + ji];
        for (int bi = 0; bi < 8; ++bi)
          logits[(size_t)(tb * 8 + bi) * 50000 + j + ji] = acc[bi][ji] + fb;
      }
    }
  }
}

extern "C" void kernel_launch(void* const* d_in, const int* in_sizes, int n_in,
                              void* d_out, int out_size, void* d_ws, size_t ws_size,
                              hipStream_t stream) {
  const int*   x    = (const int*)  d_in[0];
  const float* cfwd = (const float*)d_in[1];
  const float* cbwd = (const float*)d_in[2];
  const float* enc  = (const float*)d_in[3];
  const float* emb  = (const float*)d_in[4];
  const float* W1w  = (const float*)d_in[5];
  const float* W1b  = (const float*)d_in[6];
  const float* W2w  = (const float*)d_in[7];
  const float* W2b  = (const float*)d_in[8];
  const float* W3w  = (const float*)d_in[9];
  const float* W3b  = (const float*)d_in[10];
  const float* Vw   = (const float*)d_in[11];
  const float* Vb   = (const float*)d_in[12];
  const float* Kf   = (const float*)d_in[13];
  const float* bfv  = (const float*)d_in[14];
  const float* Kb   = (const float*)d_in[15];
  const float* bbv  = (const float*)d_in[16];
  const float* fcw  = (const float*)d_in[17];
  const float* fcb  = (const float*)d_in[18];
  float* out = (float*)d_out;

  const bool haveWs = (ws_size >= SCRATCH_BYTES);
  float* S = haveWs ? (float*)d_ws : out;   // fallback carve ends 3065856 < 3200000
  u16*   w1p   = (u16*)S;
  float* hpb   = S + OF_HPB;
  float* ctxp  = S + OF_CTXP;
  float* stats = S + OF_STATS;
  float* xin   = S + OF_XIN;
  float* zpart = S + OF_ZPART;
  u16*   hhl   = (u16*)(S + OF_HHL);

  k_prep<<<128, 256, 0, stream>>>(W1w, w1p, cfwd, cbwd, W2w, W2b, W3w, W3b, W1b, hpb);
  k_attn<<<2048, 512, 0, stream>>>(enc, w1p, hpb, Vw, Vb, ctxp, stats);
  k_attn_reduce<<<64, 256, 0, stream>>>(ctxp, stats, x, emb, xin);
  k_lstm_gemm<<<256, 256, 0, stream>>>(xin, Kf, Kb, zpart);
  k_gates<<<128, 512, 0, stream>>>(zpart, bfv, bbv, out, hhl);
  if (haveWs) k_fc_mfma<<<392, 256, 0, stream>>>(fcw, hhl, fcb, out);
  else        k_fc_f32<<<391, 256, 0, stream>>>(out, fcw, fcb, out);
}